// Round 1
// baseline (274.993 us; speedup 1.0000x reference)
//
#include <hip/hip_runtime.h>
#include <hip/hip_bf16.h>

// Problem constants (fixed by reference): m=64 rows + 1 target row = 65 rows,
// each of N = 4096*128 = 524288 f32. time_points (d_in[2]) is unused by the
// reference (time column cancels in all pairwise differences).
#define NROW 65
#define GP   80            // padded gram dim (5 tiles of 16)
#define GE   (GP * GP)     // 6400 f32 per gram copy
#define CH   128           // f32 elements per row per K-chunk
#define NT   256           // threads per block (4 waves)
#define GRID 512

typedef float  f32x4  __attribute__((ext_vector_type(4)));
typedef __bf16 bf16x8 __attribute__((ext_vector_type(8)));
typedef __bf16 bf16x4 __attribute__((ext_vector_type(4)));

// XOR-swizzle: breaks the 16-way bank conflict of 256B-stride rows under
// ds_read_b128 (guide §6 G4). Flips byte bits 4-6; preserves 8B/16B alignment.
__device__ __forceinline__ int swz(int row, int byte) {
  return byte ^ ((row & 7) << 4);
}

__global__ void zero_ws(float* __restrict__ p, int n) {
  int i = blockIdx.x * blockDim.x + threadIdx.x;
  int stride = gridDim.x * blockDim.x;
  for (; i < n; i += stride) p[i] = 0.f;
}

__global__ __launch_bounds__(NT) void gram_k(
    const float* __restrict__ X,   // [64][Nk] f32
    const float* __restrict__ T,   // [Nk] f32
    float* __restrict__ G,         // ncopies * GE f32 accumulators (zeroed)
    int ncopies, int Nk, int nchunks)
{
  // smem: staging = 80 rows * 256 B = 20480 B; reused as [80][80] f32 (25600 B)
  // for the end-of-kernel block reduction.
  __shared__ __align__(16) char smem[GE * 4];
  const int tid  = threadIdx.x;
  const int wv   = tid >> 6;     // wave 0..3 -> K-step within chunk
  const int lane = tid & 63;

  f32x4 acc[15];                 // upper-triangle 16x16 tiles (I<=J), f32
#pragma unroll
  for (int i = 0; i < 15; ++i) acc[i] = (f32x4){0.f, 0.f, 0.f, 0.f};

  // Zero pad rows 65..79 once; never overwritten by staging.
  for (int e = tid; e < (GP - NROW) * 32; e += NT) {
    int row = NROW + (e >> 5);
    int b = swz(row, row * 256 + (e & 31) * 8);
    *(unsigned long long*)(smem + b) = 0ULL;
  }

  for (int c = blockIdx.x; c < nchunks; c += gridDim.x) {
    const int k0 = c * CH;
    // Stage 65 rows x 128 f32 -> bf16 into swizzled LDS.
    // 65*32 = 2080 quad-loads; 8 full rounds of 256 + 32-thread tail.
#pragma unroll
    for (int it = 0; it < 8; ++it) {
      int q   = it * NT + tid;          // < 2048, always valid
      int row = q >> 5, k4 = q & 31;
      const float* src = (row < 64) ? (X + (size_t)row * Nk + k0 + k4 * 4)
                                    : (T + k0 + k4 * 4);
      f32x4 v = *(const f32x4*)src;
      bf16x4 h = {(__bf16)v.x, (__bf16)v.y, (__bf16)v.z, (__bf16)v.w};
      *(bf16x4*)(smem + swz(row, row * 256 + k4 * 8)) = h;
    }
    if (tid < 32) {                      // tail: last 32 quads of the t-row
      int k4 = tid;
      f32x4 v = *(const f32x4*)(T + k0 + k4 * 4);
      bf16x4 h = {(__bf16)v.x, (__bf16)v.y, (__bf16)v.z, (__bf16)v.w};
      *(bf16x4*)(smem + swz(64, 64 * 256 + k4 * 8)) = h;
    }
    __syncthreads();

    // Each wave: one K=32 step. Frag layout (16x16x32 bf16, m89-verified
    // pattern): lane holds 8 consecutive k of row (lane&15), k-group lane>>4.
    // B-frag of tile J == A-frag of tile J since B = Y^T.
    bf16x8 f[5];
#pragma unroll
    for (int t = 0; t < 5; ++t) {
      int row = t * 16 + (lane & 15);
      int b = swz(row, row * 256 + wv * 64 + (lane >> 4) * 16);
      f[t] = *(const bf16x8*)(smem + b);
    }
#pragma unroll
    for (int I = 0; I < 5; ++I)
#pragma unroll
      for (int J = I; J < 5; ++J) {
        const int idx = I * 5 + J - (I * (I + 1)) / 2;   // compile-time
        acc[idx] = __builtin_amdgcn_mfma_f32_16x16x32_bf16(f[I], f[J], acc[idx], 0, 0, 0);
      }
    __syncthreads();
  }

  // Block-level reduction: 4 waves' partials -> LDS [80][80], then ~2145
  // global atomics per block (i<=j, j<65) into 1 of ncopies buffers.
  float* gl = (float*)smem;
  for (int e = tid; e < GE; e += NT) gl[e] = 0.f;
  __syncthreads();
#pragma unroll
  for (int I = 0; I < 5; ++I)
#pragma unroll
    for (int J = I; J < 5; ++J) {
      const int idx = I * 5 + J - (I * (I + 1)) / 2;
#pragma unroll
      for (int r = 0; r < 4; ++r) {
        int grow = I * 16 + (lane >> 4) * 4 + r;  // C/D: row=(lane>>4)*4+reg
        int gcol = J * 16 + (lane & 15);          //      col=lane&15
        atomicAdd(&gl[grow * GP + gcol], acc[idx][r]);
      }
    }
  __syncthreads();
  float* dst = G + (size_t)(blockIdx.x % ncopies) * GE;
  for (int e = tid; e < GE; e += NT) {
    int i = e / GP, j = e % GP;
    if (j < NROW && i <= j) atomicAdd(dst + e, gl[e]);
  }
}

__global__ __launch_bounds__(NT) void epilogue_k(
    const float* __restrict__ G, int ncopies, float* __restrict__ out)
{
  __shared__ float gl[GE];
  __shared__ float rx[4], rt[4];
  const int tid = threadIdx.x;
  for (int e = tid; e < GE; e += NT) {
    float s = 0.f;
    for (int c = 0; c < ncopies; ++c) s += G[(size_t)c * GE + e];
    gl[e] = s;
  }
  __syncthreads();

  float accX = 0.f, accT = 0.f;
  for (int e = tid; e < GE; e += NT) {
    int i = e / GP, j = e % GP;
    if (j >= NROW || i >= j) continue;           // upper triangle, i<j
    float g  = gl[e];
    float d2 = gl[i * GP + i] + gl[j * GP + j] - 2.f * g;
    if (j < 64) {                                // pair term (i<j<64)
      accX += expf(-fmaxf(d2, 0.f));             // ref clamps d2 at 0
    } else {                                     // j==64: target term
      accT += expf(-d2);                         // ref does not clamp dt2
    }
  }
#pragma unroll
  for (int off = 32; off > 0; off >>= 1) {
    accX += __shfl_down(accX, off);
    accT += __shfl_down(accT, off);
  }
  const int wv = tid >> 6, lane = tid & 63;
  if (lane == 0) { rx[wv] = accX; rt[wv] = accT; }
  __syncthreads();
  if (tid == 0) {
    float sx = rx[0] + rx[1] + rx[2] + rx[3];
    float st = rt[0] + rt[1] + rt[2] + rt[3];
    // cross = (LAMBDA/2) * 2*sx / (m(m-1)) = 0.25*2*sx/4032 = sx/8064
    float score = sx / 8064.f - st / 64.f;
    score = fminf(fmaxf(score, -10.f), 10.f);
    out[0] = score;
  }
}

extern "C" void kernel_launch(void* const* d_in, const int* in_sizes, int n_in,
                              void* d_out, int out_size, void* d_ws, size_t ws_size,
                              hipStream_t stream) {
  const float* X = (const float*)d_in[0];   // generated_samples [64,4096,128]
  const float* T = (const float*)d_in[1];   // target_sample [4096,128]
  // d_in[2] (time_points) is mathematically unused by the reference.
  float* out = (float*)d_out;
  float* G   = (float*)d_ws;

  const int Nk = in_sizes[1];               // S*D = 524288
  const int nchunks = Nk / CH;              // 4096

  int NC = (int)(ws_size / (GE * sizeof(float)));
  if (NC > 4) NC = 4;
  if (NC < 1) NC = 1;

  zero_ws<<<32, NT, 0, stream>>>(G, NC * GE);
  gram_k<<<GRID, NT, 0, stream>>>(X, T, G, NC, Nk, nchunks);
  epilogue_k<<<1, NT, 0, stream>>>(G, NC, out);
}